// Round 5
// baseline (732.778 us; speedup 1.0000x reference)
//
#include <hip/hip_runtime.h>

#define HW40 1600
typedef unsigned short ushort_t;
typedef __attribute__((ext_vector_type(8))) short short8;
typedef __attribute__((ext_vector_type(4))) short short4v;
typedef __attribute__((ext_vector_type(4))) float f4v;

__device__ __forceinline__ float bu(ushort_t u) {
  union { unsigned i; float f; } x; x.i = ((unsigned)u) << 16; return x.f;
}
__device__ __forceinline__ ushort_t fb(float f) {
  union { float f; unsigned i; } x; x.f = f;
  unsigned r = x.i + 0x7FFFu + ((x.i >> 16) & 1u);
  return (ushort_t)(r >> 16);
}

#define GLD16(g, l)                                                            \
  __builtin_amdgcn_global_load_lds(                                            \
      (const __attribute__((address_space(1))) void*)(g),                      \
      (__attribute__((address_space(3))) void*)(l), 16, 0, 0)

#define PART_STRIDE 1638400  // one split-K slice: 256 x 6400

// ---------------------------------------------------------------------------
// 3x3 conv weights [co][cin][3][3] fp32 -> A[co][tap*256+cin] bf16, pad rows.
// ---------------------------------------------------------------------------
__global__ void convert_w9(const float* __restrict__ src, ushort_t* __restrict__ dst,
                           int Cout_src, int Cout_pad) {
  int idx = blockIdx.x * 256 + threadIdx.x;
  if (idx >= Cout_pad * 2304) return;
  int co = idx / 2304;
  int k  = idx - co * 2304;
  int cin = k & 255, tap = k >> 8;
  dst[idx] = (co < Cout_src) ? fb(src[(size_t)co * 2304 + cin * 9 + tap]) : (ushort_t)0;
}

// ---------------------------------------------------------------------------
// dcn weights [co][cin][16] fp32 -> A_bf16 [co][k = i*256 + cin]
// ---------------------------------------------------------------------------
__global__ __launch_bounds__(256) void convert_dcnw(const float* __restrict__ w0,
                                                    const float* __restrict__ w1,
                                                    ushort_t* __restrict__ A0,
                                                    ushort_t* __restrict__ A1) {
  __shared__ float s[4096];
  const int co = blockIdx.x & 255;
  const float* w = (blockIdx.x < 256) ? w0 : w1;
  ushort_t* A = (blockIdx.x < 256) ? A0 : A1;
  const int t = threadIdx.x;
  const float4* wp = (const float4*)(w + (size_t)co * 4096);
#pragma unroll
  for (int q = 0; q < 4; ++q) ((float4*)s)[t + q * 256] = wp[t + q * 256];
  __syncthreads();
  const int i = t >> 4, cb = (t & 15) * 16;
  ushort_t tmp[16];
#pragma unroll
  for (int j = 0; j < 16; ++j) tmp[j] = fb(s[(cb + j) * 16 + i]);
  ushort_t* op = A + (size_t)co * 4096 + t * 16;
  ((uint4*)op)[0] = ((uint4*)tmp)[0];
  ((uint4*)op)[1] = ((uint4*)tmp)[1];
}

// ---------------------------------------------------------------------------
// NCHW fp32 -> NHWC bf16 (prep only, for f0/f1 gather sources).
// ---------------------------------------------------------------------------
__global__ __launch_bounds__(256) void nhwc_bf16_kernel(const float* __restrict__ x,
                                                        ushort_t* __restrict__ xt, int HW) {
  __shared__ float tile[32][33];
  const int s0 = blockIdx.x * 32, c0 = blockIdx.y * 32, b = blockIdx.z;
  const int tx = threadIdx.x & 31, ty = threadIdx.x >> 5;
  const float* xb = x + ((size_t)b * 256 + c0) * HW + s0;
#pragma unroll
  for (int q = 0; q < 4; ++q) tile[ty + q * 8][tx] = xb[(size_t)(ty + q * 8) * HW + tx];
  __syncthreads();
  ushort_t* ob = xt + ((size_t)b * HW + s0) * 256 + c0;
#pragma unroll
  for (int q = 0; q < 4; ++q) {
    int srow = ty + q * 8;
    ob[(size_t)srow * 256 + tx] = fb(tile[tx][srow]);
  }
}

// ---------------------------------------------------------------------------
// Fused im2col: NCHW fp32 (40x40) -> colC bf16 [n][tap*256+cin], 3x3 s1 p1.
// grid (40 h, 2 cin-half, 4 b), block 256.
// LDS [y 0..2][x 0..41][cin 0..127] bf16 = 32.25 KB; zero halo built on load.
// Load: lanes = consecutive cin -> 128B-contig ds_write (conflict-free).
// Store: 16-lane groups read 256B-contig ds_read_b128.
// ---------------------------------------------------------------------------
__global__ __launch_bounds__(256) void im2col40f(const float* __restrict__ src,
                                                 ushort_t* __restrict__ colC) {
  __shared__ ushort_t s[3 * 42 * 128];
  const int h = blockIdx.x, half = blockIdx.y, b = blockIdx.z;
  const int t = threadIdx.x;
  for (int sid = t; sid < 384; sid += 256) {
    const int cin = sid & 127, y = sid >> 7;
    const int yin = h - 1 + y;
    const bool rv = (yin >= 0 && yin < 40);
    const float* rp = src + ((size_t)(b * 256 + half * 128 + cin) * 1600 + yin * 40);
    ushort_t* sp = s + y * 42 * 128 + cin;
#pragma unroll 7
    for (int lx = 0; lx < 42; ++lx) {
      int xin = lx - 1;
      float v = (rv && xin >= 0 && xin < 40) ? rp[xin] : 0.f;
      sp[lx * 128] = fb(v);
    }
  }
  __syncthreads();
  const size_t nbase = (size_t)b * 1600 + h * 40;
  for (int c = t; c < 5760; c += 256) {
    const int px = c / 144;
    const int r = c - px * 144;
    const int tap = r >> 4, cin8 = (r & 15) * 8;
    const int ky = tap / 3, kx = tap - ky * 3;
    short8 v = *(const short8*)(s + ((ky * 42) + px + kx) * 128 + cin8);
    *(short8*)(colC + (nbase + px) * 2304 + tap * 256 + half * 128 + cin8) = v;
  }
}

// ---------------------------------------------------------------------------
// Sampler (fused com-epilogue): geometry = bias + sum of 4 bf16 GEMM partial
// slices (dy,dx raw; mask sigmoided); then bilinear-gathers NHWC-bf16 xt into
// colT[n][k=i*256+cin]. grid (100 px-tiles of 16, B), block 256.
// ---------------------------------------------------------------------------
__global__ __launch_bounds__(256) void sample_kernel(
    const ushort_t* __restrict__ xt, const ushort_t* __restrict__ part,
    const float* __restrict__ cbias, ushort_t* __restrict__ colT,
    int Hin, int Win, int stride, int pad, int dil) {
  __shared__ int4  gL[256];
  __shared__ float4 gW[256];
  const int b = blockIdx.y;
  const int px0 = blockIdx.x * 16;
  const int t = threadIdx.x;
  const int HWin = Hin * Win;

  {
    const int px_l = t & 15, i = t >> 4;
    const int p = px0 + px_l;
    const int n = b * 1600 + p;
    const int ph = p / 40, pw = p - (p / 40) * 40;
    float dy = cbias[2 * i], dx = cbias[2 * i + 1], mzr = cbias[32 + i];
#pragma unroll
    for (int kz = 0; kz < 4; ++kz) {
      const ushort_t* pp = part + (size_t)kz * PART_STRIDE + n;
      dy  += bu(pp[(size_t)(2 * i) * 6400]);
      dx  += bu(pp[(size_t)(2 * i + 1) * 6400]);
      mzr += bu(pp[(size_t)(32 + i) * 6400]);
    }
    float mz = 1.f / (1.f + expf(-mzr));
    float py = (float)(ph * stride - pad + (i >> 2) * dil) + dy;
    float px = (float)(pw * stride - pad + (i & 3) * dil) + dx;
    float y0f = floorf(py), x0f = floorf(px);
    float ly = py - y0f, lx = px - x0f;
    int y0 = (int)y0f, x0 = (int)x0f;
    int y1 = y0 + 1, x1 = x0 + 1;
    float hy = 1.f - ly, hx = 1.f - lx;
    float w00 = hy * hx * mz, w01 = hy * lx * mz;
    float w10 = ly * hx * mz, w11 = ly * lx * mz;
    if (y0 < 0 || y0 >= Hin) { w00 = 0.f; w01 = 0.f; }
    if (y1 < 0 || y1 >= Hin) { w10 = 0.f; w11 = 0.f; }
    if (x0 < 0 || x0 >= Win) { w00 = 0.f; w10 = 0.f; }
    if (x1 < 0 || x1 >= Win) { w01 = 0.f; w11 = 0.f; }
    int cy0 = min(max(y0, 0), Hin - 1), cy1 = min(max(y1, 0), Hin - 1);
    int cx0 = min(max(x0, 0), Win - 1), cx1 = min(max(x1, 0), Win - 1);
    gL[t] = make_int4((cy0 * Win + cx0) * 256, (cy0 * Win + cx1) * 256,
                      (cy1 * Win + cx0) * 256, (cy1 * Win + cx1) * 256);
    gW[t] = make_float4(w00, w01, w10, w11);
  }
  __syncthreads();

  const ushort_t* xtb = xt + (size_t)b * HWin * 256;
  const int wv = t >> 6, l = t & 63;
  const int half = l >> 5;
  const int cin8 = (l & 31) * 8;

#pragma unroll 2
  for (int it = 0; it < 32; ++it) {
    const int pr = it * 8 + wv * 2 + half;
    const int4 G = gL[pr];
    const float4 W = gW[pr];
    short8 c00 = *(const short8*)(xtb + G.x + cin8);
    short8 c01 = *(const short8*)(xtb + G.y + cin8);
    short8 c10 = *(const short8*)(xtb + G.z + cin8);
    short8 c11 = *(const short8*)(xtb + G.w + cin8);
    short8 rr;
#pragma unroll
    for (int j = 0; j < 8; ++j) {
      float v = W.x * bu((ushort_t)c00[j]) + W.y * bu((ushort_t)c01[j]) +
                W.z * bu((ushort_t)c10[j]) + W.w * bu((ushort_t)c11[j]);
      rr[j] = (short)fb(v);
    }
    const int px_l = pr & 15, i = pr >> 4;
    *(short8*)(colT + ((size_t)(b * 1600 + px0 + px_l) * 4096 + i * 256 + cin8)) = rr;
  }
}

// ---------------------------------------------------------------------------
// Generic bf16 MFMA GEMM, split-K = gridDim.z, bf16 partials.
// K-chunk swizzle: logical 16B chunk q of row r at slot (q+(r>>1))&3 ->
// ds_read_b128 worst aliasing 2-way (free). grid (50, M/MTILE, KZ).
// ---------------------------------------------------------------------------
template <int MTILE>
__global__ __launch_bounds__(256) void gemm_bt(const ushort_t* __restrict__ A,
                                               const ushort_t* __restrict__ B,
                                               ushort_t* __restrict__ part,
                                               int ksteps, int K) {
  constexpr int FN = (MTILE == 128) ? 4 : 2;
  __shared__ ushort_t sA[MTILE * 32];
  __shared__ ushort_t sB[128 * 32];
  const int nt = blockIdx.x, mt = blockIdx.y, kz = blockIdx.z;
  const int t = threadIdx.x;
  const int wv = t >> 6, l = t & 63;
  const int wm = (MTILE == 128) ? (wv >> 1) : 0;
  const int wn = (MTILE == 128) ? (wv & 1) : wv;

  f4v acc[4][FN];
#pragma unroll
  for (int a = 0; a < 4; ++a)
#pragma unroll
    for (int bb = 0; bb < FN; ++bb) acc[a][bb] = (f4v)(0.f);

  const int ra = t >> 2;
  const int q  = ((t & 3) - (ra >> 1)) & 3;
  const size_t aoff = (size_t)(mt * MTILE + ra) * K + q * 8;
  const size_t boff = (size_t)(nt * 128 + ra) * K + q * 8;
  ushort_t* lA = sA + t * 8;
  ushort_t* lB = sB + t * 8;

  int k0 = kz * ksteps * 32;
  const int lm = l & 15;
  const int koff = (((l >> 4) + (lm >> 1)) & 3) * 8;

  for (int step = 0; step < ksteps; ++step, k0 += 32) {
    __syncthreads();
    GLD16(A + aoff + k0, lA);
    if (MTILE == 128) GLD16(A + aoff + (size_t)64 * K + k0, lA + 2048);
    GLD16(B + boff + k0, lB);
    GLD16(B + boff + (size_t)64 * K + k0, lB + 2048);
    __syncthreads();
    short8 af[4], bfr[FN];
#pragma unroll
    for (int fm = 0; fm < 4; ++fm)
      af[fm] = *(const short8*)(sA + (wm * 64 + fm * 16 + lm) * 32 + koff);
#pragma unroll
    for (int fn = 0; fn < FN; ++fn)
      bfr[fn] = *(const short8*)(sB + (wn * (16 * FN) + fn * 16 + lm) * 32 + koff);
#pragma unroll
    for (int fm = 0; fm < 4; ++fm)
#pragma unroll
      for (int fn = 0; fn < FN; ++fn)
        acc[fm][fn] = __builtin_amdgcn_mfma_f32_16x16x32_bf16(af[fm], bfr[fn],
                                                              acc[fm][fn], 0, 0, 0);
  }

  const int row_l = (l >> 4) * 4;
  ushort_t* pb = part + (size_t)kz * PART_STRIDE;
#pragma unroll
  for (int fm = 0; fm < 4; ++fm) {
#pragma unroll
    for (int fn = 0; fn < FN; ++fn) {
      const int n = nt * 128 + wn * (16 * FN) + fn * 16 + lm;
#pragma unroll
      for (int r = 0; r < 4; ++r) {
        const int m = mt * MTILE + wm * 64 + fm * 16 + row_l + r;
        pb[(size_t)m * 6400 + n] = fb(acc[fm][fn][r]);
      }
    }
  }
}

// ---------------------------------------------------------------------------
// GEMM epilogue: dst = (relu? max(sum8+bias,0) : sum8+bias) + src
// grid (2, 256, B), block 256.
// ---------------------------------------------------------------------------
__global__ __launch_bounds__(256) void gemm_epilogue(const ushort_t* __restrict__ part,
                                                     const float* __restrict__ bias,
                                                     const float* __restrict__ src,
                                                     float* __restrict__ dst, int relu) {
  const int co = blockIdx.y, b = blockIdx.z;
  const int idx = blockIdx.x * 256 + threadIdx.x;
  if (idx >= 400) return;
  const int p = idx * 4;
  const size_t n = (size_t)b * 1600 + p;
  float a[4] = {0.f, 0.f, 0.f, 0.f};
#pragma unroll
  for (int kz = 0; kz < 8; ++kz) {
    short4v pp = *(const short4v*)(part + (size_t)kz * PART_STRIDE + (size_t)co * 6400 + n);
#pragma unroll
    for (int j = 0; j < 4; ++j) a[j] += bu((ushort_t)pp[j]);
  }
  float bv = bias[co];
  const size_t fo = ((size_t)b * 256 + co) * 1600 + p;
  float4 s = *(const float4*)(src + fo);
  float4 o;
  if (relu) {
    o.x = fmaxf(a[0] + bv, 0.f) + s.x;
    o.y = fmaxf(a[1] + bv, 0.f) + s.y;
    o.z = fmaxf(a[2] + bv, 0.f) + s.z;
    o.w = fmaxf(a[3] + bv, 0.f) + s.w;
  } else {
    o.x = a[0] + bv + s.x;
    o.y = a[1] + bv + s.y;
    o.z = a[2] + bv + s.z;
    o.w = a[3] + bv + s.w;
  }
  *(float4*)(dst + fo) = o;
}

// ---------------------------------------------------------------------------
extern "C" void kernel_launch(void* const* d_in, const int* in_sizes, int n_in,
                              void* d_out, int out_size, void* d_ws, size_t ws_size,
                              hipStream_t stream) {
  (void)in_sizes; (void)n_in; (void)out_size; (void)ws_size;
  const float* f0     = (const float*)d_in[0];
  const float* f1     = (const float*)d_in[1];
  const float* f2     = (const float*)d_in[2];
  const float* com_w0 = (const float*)d_in[3];
  const float* com_b0 = (const float*)d_in[4];
  const float* com_w1 = (const float*)d_in[5];
  const float* com_b1 = (const float*)d_in[6];
  const float* dcn_w0 = (const float*)d_in[7];
  const float* dcn_b0 = (const float*)d_in[8];
  const float* dcn_w1 = (const float*)d_in[9];
  const float* dcn_b1 = (const float*)d_in[10];
  const float* res_w  = (const float*)d_in[11];
  const float* res_b  = (const float*)d_in[12];
  float* out = (float*)d_out;
  float* ws  = (float*)d_ws;

  // ws layout (float offsets); ~39.3M floats ~= 157 MB
  float*    fbuf  = ws + 0;          // 1,638,400 f32
  ushort_t* A0    = (ushort_t*)(ws + 1700000);   // 1,048,576 u16
  ushort_t* A1    = (ushort_t*)(ws + 2230000);   // 1,048,576 u16
  ushort_t* Acom0 = (ushort_t*)(ws + 2760000);   //   147,456 u16 (64x2304)
  ushort_t* Acom1 = (ushort_t*)(ws + 2840000);   //   147,456 u16
  ushort_t* Ares  = (ushort_t*)(ws + 2920000);   //   589,824 u16 (256x2304)
  ushort_t* f1t   = (ushort_t*)(ws + 3220000);   // 6,553,600 u16
  ushort_t* f0t   = (ushort_t*)(ws + 6500000);   // 26,214,400 u16
  ushort_t* colB  = (ushort_t*)(ws + 19610000);  // 26,214,400 u16 (colC/colT share)
  ushort_t* part  = (ushort_t*)(ws + 32720000);  // 13,107,200 u16 (8 bf16 slices)

  convert_w9<<<(64 * 2304 + 255) / 256, 256, 0, stream>>>(com_w0, Acom0, 48, 64);
  convert_w9<<<(64 * 2304 + 255) / 256, 256, 0, stream>>>(com_w1, Acom1, 48, 64);
  convert_w9<<<(256 * 2304 + 255) / 256, 256, 0, stream>>>(res_w, Ares, 256, 256);
  convert_dcnw<<<512, 256, 0, stream>>>(dcn_w0, dcn_w1, A0, A1);
  nhwc_bf16_kernel<<<dim3(200, 8, 4), 256, 0, stream>>>(f1, f1t, 6400);
  nhwc_bf16_kernel<<<dim3(800, 8, 4), 256, 0, stream>>>(f0, f0t, 25600);

  const float* fsrc = f2;
  for (int s = 0; s < 4; ++s) {
    int l = s & 1;
    // com conv as GEMM (M=48 pad 64, K=2304, split-K 4)
    im2col40f<<<dim3(40, 2, 4), 256, 0, stream>>>(fsrc, colB);
    gemm_bt<64><<<dim3(50, 1, 4), 256, 0, stream>>>(l ? Acom1 : Acom0, colB, part, 18, 2304);
    // sampler fuses com epilogue (bias + partial-sum + sigmoid)
    if (l == 0) {
      sample_kernel<<<dim3(100, 4), 256, 0, stream>>>(f1t, part, com_b0, colB, 80, 80, 2, 1, 1);
    } else {
      sample_kernel<<<dim3(100, 4), 256, 0, stream>>>(f0t, part, com_b1, colB, 160, 160, 4, 3, 3);
    }
    // deformable conv GEMM (K=4096, split-K 8)
    gemm_bt<128><<<dim3(50, 2, 8), 256, 0, stream>>>(l ? A1 : A0, colB, part, 16, 4096);
    gemm_epilogue<<<dim3(2, 256, 4), 256, 0, stream>>>(part, l ? dcn_b1 : dcn_b0, fsrc, fbuf, 1);
    fsrc = fbuf;
  }
  // res conv as GEMM (M=256, K=2304, split-K 8), epilogue adds f2 (fh)
  im2col40f<<<dim3(40, 2, 4), 256, 0, stream>>>(fbuf, colB);
  gemm_bt<128><<<dim3(50, 2, 8), 256, 0, stream>>>(Ares, colB, part, 9, 2304);
  gemm_epilogue<<<dim3(2, 256, 4), 256, 0, stream>>>(part, res_b, f2, out, 0);
}

// Round 6
// 676.207 us; speedup vs baseline: 1.0837x; 1.0837x over previous
//
#include <hip/hip_runtime.h>

#define HW40 1600
typedef unsigned short ushort_t;
typedef __attribute__((ext_vector_type(8))) short short8;
typedef __attribute__((ext_vector_type(4))) short short4v;
typedef __attribute__((ext_vector_type(4))) float f4v;

__device__ __forceinline__ float bu(ushort_t u) {
  union { unsigned i; float f; } x; x.i = ((unsigned)u) << 16; return x.f;
}
__device__ __forceinline__ ushort_t fb(float f) {
  union { float f; unsigned i; } x; x.f = f;
  unsigned r = x.i + 0x7FFFu + ((x.i >> 16) & 1u);
  return (ushort_t)(r >> 16);
}

#define GLD16(g, l)                                                            \
  __builtin_amdgcn_global_load_lds(                                            \
      (const __attribute__((address_space(1))) void*)(g),                      \
      (__attribute__((address_space(3))) void*)(l), 16, 0, 0)

#define PART_STRIDE 1638400  // one split-K slice: 256 x 6400

// ---------------------------------------------------------------------------
// 3x3 conv weights [co][cin][3][3] fp32 -> A[co][tap*256+cin] bf16, pad rows.
// ---------------------------------------------------------------------------
__global__ void convert_w9(const float* __restrict__ src, ushort_t* __restrict__ dst,
                           int Cout_src, int Cout_pad) {
  int idx = blockIdx.x * 256 + threadIdx.x;
  if (idx >= Cout_pad * 2304) return;
  int co = idx / 2304;
  int k  = idx - co * 2304;
  int cin = k & 255, tap = k >> 8;
  dst[idx] = (co < Cout_src) ? fb(src[(size_t)co * 2304 + cin * 9 + tap]) : (ushort_t)0;
}

// ---------------------------------------------------------------------------
// dcn weights [co][cin][16] fp32 -> A_bf16 [co][k = i*256 + cin]
// ---------------------------------------------------------------------------
__global__ __launch_bounds__(256) void convert_dcnw(const float* __restrict__ w0,
                                                    const float* __restrict__ w1,
                                                    ushort_t* __restrict__ A0,
                                                    ushort_t* __restrict__ A1) {
  __shared__ float s[4096];
  const int co = blockIdx.x & 255;
  const float* w = (blockIdx.x < 256) ? w0 : w1;
  ushort_t* A = (blockIdx.x < 256) ? A0 : A1;
  const int t = threadIdx.x;
  const float4* wp = (const float4*)(w + (size_t)co * 4096);
#pragma unroll
  for (int q = 0; q < 4; ++q) ((float4*)s)[t + q * 256] = wp[t + q * 256];
  __syncthreads();
  const int i = t >> 4, cb = (t & 15) * 16;
  ushort_t tmp[16];
#pragma unroll
  for (int j = 0; j < 16; ++j) tmp[j] = fb(s[(cb + j) * 16 + i]);
  ushort_t* op = A + (size_t)co * 4096 + t * 16;
  ((uint4*)op)[0] = ((uint4*)tmp)[0];
  ((uint4*)op)[1] = ((uint4*)tmp)[1];
}

// ---------------------------------------------------------------------------
// NCHW fp32 -> NHWC bf16:  xt[b][s][c] = bf16(x[b][c][s])
// ---------------------------------------------------------------------------
__global__ __launch_bounds__(256) void nhwc_bf16_kernel(const float* __restrict__ x,
                                                        ushort_t* __restrict__ xt, int HW) {
  __shared__ float tile[32][33];
  const int s0 = blockIdx.x * 32, c0 = blockIdx.y * 32, b = blockIdx.z;
  const int tx = threadIdx.x & 31, ty = threadIdx.x >> 5;
  const float* xb = x + ((size_t)b * 256 + c0) * HW + s0;
#pragma unroll
  for (int q = 0; q < 4; ++q) tile[ty + q * 8][tx] = xb[(size_t)(ty + q * 8) * HW + tx];
  __syncthreads();
  ushort_t* ob = xt + ((size_t)b * HW + s0) * 256 + c0;
#pragma unroll
  for (int q = 0; q < 4; ++q) {
    int srow = ty + q * 8;
    ob[(size_t)srow * 256 + tx] = fb(tile[tx][srow]);
  }
}

// ---------------------------------------------------------------------------
// im2col for 3x3 s1 p1 on 40x40 NHWC-bf16 feature (proven R4 path).
// ---------------------------------------------------------------------------
__global__ __launch_bounds__(256) void im2col40(const ushort_t* __restrict__ ft,
                                                ushort_t* __restrict__ colC) {
  const int b = blockIdx.y;
  const int px0 = blockIdx.x * 16;
  const int t = threadIdx.x;
  const int c8 = (t & 31) * 8;
  const int r  = t >> 5;
  const ushort_t* fb_ = ft + (size_t)b * 1600 * 256;
#pragma unroll 2
  for (int it = 0; it < 18; ++it) {
    int rc = it * 8 + r;
    int px_l = rc / 9;
    int tap  = rc - px_l * 9;
    int p  = px0 + px_l;
    int ph = p / 40, pw = p - (p / 40) * 40;
    int ky = tap / 3, kx = tap - (tap / 3) * 3;
    int y = ph + ky - 1, xq = pw + kx - 1;
    short8 v = (short8)(0);
    if (y >= 0 && y < 40 && xq >= 0 && xq < 40)
      v = *(const short8*)(fb_ + (size_t)(y * 40 + xq) * 256 + c8);
    *(short8*)(colC + ((size_t)(b * 1600 + p) * 2304 + tap * 256 + c8)) = v;
  }
}

// ---------------------------------------------------------------------------
// Sampler (fused com-epilogue): geometry = bias + sum of 4 bf16 GEMM partial
// slices; then bilinear-gathers NHWC-bf16 xt into colT[n][k=i*256+cin].
// 8-px tiles for occupancy: grid (200, B) = 800 blocks, block 256.
// ---------------------------------------------------------------------------
__global__ __launch_bounds__(256) void sample_kernel(
    const ushort_t* __restrict__ xt, const ushort_t* __restrict__ part,
    const float* __restrict__ cbias, ushort_t* __restrict__ colT,
    int Hin, int Win, int stride, int pad, int dil) {
  __shared__ int4  gL[128];
  __shared__ float4 gW[128];
  const int b = blockIdx.y;
  const int px0 = blockIdx.x * 8;
  const int t = threadIdx.x;
  const int HWin = Hin * Win;

  if (t < 128) {  // geometry: pair pid = t -> (px_l = t&7, tap i = t>>3)
    const int px_l = t & 7, i = t >> 3;
    const int p = px0 + px_l;
    const int n = b * 1600 + p;
    const int ph = p / 40, pw = p - (p / 40) * 40;
    float dy = cbias[2 * i], dx = cbias[2 * i + 1], mzr = cbias[32 + i];
#pragma unroll
    for (int kz = 0; kz < 4; ++kz) {
      const ushort_t* pp = part + (size_t)kz * PART_STRIDE + n;
      dy  += bu(pp[(size_t)(2 * i) * 6400]);
      dx  += bu(pp[(size_t)(2 * i + 1) * 6400]);
      mzr += bu(pp[(size_t)(32 + i) * 6400]);
    }
    float mz = 1.f / (1.f + expf(-mzr));
    float py = (float)(ph * stride - pad + (i >> 2) * dil) + dy;
    float px = (float)(pw * stride - pad + (i & 3) * dil) + dx;
    float y0f = floorf(py), x0f = floorf(px);
    float ly = py - y0f, lx = px - x0f;
    int y0 = (int)y0f, x0 = (int)x0f;
    int y1 = y0 + 1, x1 = x0 + 1;
    float hy = 1.f - ly, hx = 1.f - lx;
    float w00 = hy * hx * mz, w01 = hy * lx * mz;
    float w10 = ly * hx * mz, w11 = ly * lx * mz;
    if (y0 < 0 || y0 >= Hin) { w00 = 0.f; w01 = 0.f; }
    if (y1 < 0 || y1 >= Hin) { w10 = 0.f; w11 = 0.f; }
    if (x0 < 0 || x0 >= Win) { w00 = 0.f; w10 = 0.f; }
    if (x1 < 0 || x1 >= Win) { w01 = 0.f; w11 = 0.f; }
    int cy0 = min(max(y0, 0), Hin - 1), cy1 = min(max(y1, 0), Hin - 1);
    int cx0 = min(max(x0, 0), Win - 1), cx1 = min(max(x1, 0), Win - 1);
    gL[t] = make_int4((cy0 * Win + cx0) * 256, (cy0 * Win + cx1) * 256,
                      (cy1 * Win + cx0) * 256, (cy1 * Win + cx1) * 256);
    gW[t] = make_float4(w00, w01, w10, w11);
  }
  __syncthreads();

  const ushort_t* xtb = xt + (size_t)b * HWin * 256;
  const int wv = t >> 6, l = t & 63;
  const int half = l >> 5;
  const int cin8 = (l & 31) * 8;

#pragma unroll 2
  for (int it = 0; it < 16; ++it) {
    const int pr = it * 8 + wv * 2 + half;
    const int4 G = gL[pr];
    const float4 W = gW[pr];
    short8 c00 = *(const short8*)(xtb + G.x + cin8);
    short8 c01 = *(const short8*)(xtb + G.y + cin8);
    short8 c10 = *(const short8*)(xtb + G.z + cin8);
    short8 c11 = *(const short8*)(xtb + G.w + cin8);
    short8 rr;
#pragma unroll
    for (int j = 0; j < 8; ++j) {
      float v = W.x * bu((ushort_t)c00[j]) + W.y * bu((ushort_t)c01[j]) +
                W.z * bu((ushort_t)c10[j]) + W.w * bu((ushort_t)c11[j]);
      rr[j] = (short)fb(v);
    }
    const int px_l = pr & 7, i = pr >> 3;
    *(short8*)(colT + ((size_t)(b * 1600 + px0 + px_l) * 4096 + i * 256 + cin8)) = rr;
  }
}

// ---------------------------------------------------------------------------
// Generic bf16 MFMA GEMM, split-K = gridDim.z, bf16 partials.
// K-chunk swizzle: logical 16B chunk q of row r at slot (q+(r>>1))&3 ->
// ds_read_b128 worst aliasing 2-way (free). grid (50, M/MTILE, KZ).
// ---------------------------------------------------------------------------
template <int MTILE>
__global__ __launch_bounds__(256) void gemm_bt(const ushort_t* __restrict__ A,
                                               const ushort_t* __restrict__ B,
                                               ushort_t* __restrict__ part,
                                               int ksteps, int K) {
  constexpr int FN = (MTILE == 128) ? 4 : 2;
  __shared__ ushort_t sA[MTILE * 32];
  __shared__ ushort_t sB[128 * 32];
  const int nt = blockIdx.x, mt = blockIdx.y, kz = blockIdx.z;
  const int t = threadIdx.x;
  const int wv = t >> 6, l = t & 63;
  const int wm = (MTILE == 128) ? (wv >> 1) : 0;
  const int wn = (MTILE == 128) ? (wv & 1) : wv;

  f4v acc[4][FN];
#pragma unroll
  for (int a = 0; a < 4; ++a)
#pragma unroll
    for (int bb = 0; bb < FN; ++bb) acc[a][bb] = (f4v)(0.f);

  const int ra = t >> 2;
  const int q  = ((t & 3) - (ra >> 1)) & 3;
  const size_t aoff = (size_t)(mt * MTILE + ra) * K + q * 8;
  const size_t boff = (size_t)(nt * 128 + ra) * K + q * 8;
  ushort_t* lA = sA + t * 8;
  ushort_t* lB = sB + t * 8;

  int k0 = kz * ksteps * 32;
  const int lm = l & 15;
  const int koff = (((l >> 4) + (lm >> 1)) & 3) * 8;

  for (int step = 0; step < ksteps; ++step, k0 += 32) {
    __syncthreads();
    GLD16(A + aoff + k0, lA);
    if (MTILE == 128) GLD16(A + aoff + (size_t)64 * K + k0, lA + 2048);
    GLD16(B + boff + k0, lB);
    GLD16(B + boff + (size_t)64 * K + k0, lB + 2048);
    __syncthreads();
    short8 af[4], bfr[FN];
#pragma unroll
    for (int fm = 0; fm < 4; ++fm)
      af[fm] = *(const short8*)(sA + (wm * 64 + fm * 16 + lm) * 32 + koff);
#pragma unroll
    for (int fn = 0; fn < FN; ++fn)
      bfr[fn] = *(const short8*)(sB + (wn * (16 * FN) + fn * 16 + lm) * 32 + koff);
#pragma unroll
    for (int fm = 0; fm < 4; ++fm)
#pragma unroll
      for (int fn = 0; fn < FN; ++fn)
        acc[fm][fn] = __builtin_amdgcn_mfma_f32_16x16x32_bf16(af[fm], bfr[fn],
                                                              acc[fm][fn], 0, 0, 0);
  }

  const int row_l = (l >> 4) * 4;
  ushort_t* pb = part + (size_t)kz * PART_STRIDE;
#pragma unroll
  for (int fm = 0; fm < 4; ++fm) {
#pragma unroll
    for (int fn = 0; fn < FN; ++fn) {
      const int n = nt * 128 + wn * (16 * FN) + fn * 16 + lm;
#pragma unroll
      for (int r = 0; r < 4; ++r) {
        const int m = mt * MTILE + wm * 64 + fm * 16 + row_l + r;
        pb[(size_t)m * 6400 + n] = fb(acc[fm][fn][r]);
      }
    }
  }
}

// ---------------------------------------------------------------------------
// GEMM epilogue: dst = (relu? max(sum8+bias,0) : sum8+bias) + src
// grid (2, 256, B), block 256.
// ---------------------------------------------------------------------------
__global__ __launch_bounds__(256) void gemm_epilogue(const ushort_t* __restrict__ part,
                                                     const float* __restrict__ bias,
                                                     const float* __restrict__ src,
                                                     float* __restrict__ dst, int relu) {
  const int co = blockIdx.y, b = blockIdx.z;
  const int idx = blockIdx.x * 256 + threadIdx.x;
  if (idx >= 400) return;
  const int p = idx * 4;
  const size_t n = (size_t)b * 1600 + p;
  float a[4] = {0.f, 0.f, 0.f, 0.f};
#pragma unroll
  for (int kz = 0; kz < 8; ++kz) {
    short4v pp = *(const short4v*)(part + (size_t)kz * PART_STRIDE + (size_t)co * 6400 + n);
#pragma unroll
    for (int j = 0; j < 4; ++j) a[j] += bu((ushort_t)pp[j]);
  }
  float bv = bias[co];
  const size_t fo = ((size_t)b * 256 + co) * 1600 + p;
  float4 s = *(const float4*)(src + fo);
  float4 o;
  if (relu) {
    o.x = fmaxf(a[0] + bv, 0.f) + s.x;
    o.y = fmaxf(a[1] + bv, 0.f) + s.y;
    o.z = fmaxf(a[2] + bv, 0.f) + s.z;
    o.w = fmaxf(a[3] + bv, 0.f) + s.w;
  } else {
    o.x = a[0] + bv + s.x;
    o.y = a[1] + bv + s.y;
    o.z = a[2] + bv + s.z;
    o.w = a[3] + bv + s.w;
  }
  *(float4*)(dst + fo) = o;
}

// ---------------------------------------------------------------------------
extern "C" void kernel_launch(void* const* d_in, const int* in_sizes, int n_in,
                              void* d_out, int out_size, void* d_ws, size_t ws_size,
                              hipStream_t stream) {
  (void)in_sizes; (void)n_in; (void)out_size; (void)ws_size;
  const float* f0     = (const float*)d_in[0];
  const float* f1     = (const float*)d_in[1];
  const float* f2     = (const float*)d_in[2];
  const float* com_w0 = (const float*)d_in[3];
  const float* com_b0 = (const float*)d_in[4];
  const float* com_w1 = (const float*)d_in[5];
  const float* com_b1 = (const float*)d_in[6];
  const float* dcn_w0 = (const float*)d_in[7];
  const float* dcn_b0 = (const float*)d_in[8];
  const float* dcn_w1 = (const float*)d_in[9];
  const float* dcn_b1 = (const float*)d_in[10];
  const float* res_w  = (const float*)d_in[11];
  const float* res_b  = (const float*)d_in[12];
  float* out = (float*)d_out;
  float* ws  = (float*)d_ws;

  // ws layout (float offsets); ~40.2M floats ~= 161 MB
  float*    fbuf  = ws + 0;          // 1,638,400 f32
  ushort_t* A0    = (ushort_t*)(ws + 1700000);   // 1,048,576 u16
  ushort_t* A1    = (ushort_t*)(ws + 2230000);   // 1,048,576 u16
  ushort_t* Acom0 = (ushort_t*)(ws + 2760000);   //   147,456 u16 (64x2304)
  ushort_t* Acom1 = (ushort_t*)(ws + 2840000);   //   147,456 u16
  ushort_t* Ares  = (ushort_t*)(ws + 2920000);   //   589,824 u16 (256x2304)
  ushort_t* ft40  = (ushort_t*)(ws + 3220000);   // 1,638,400 u16
  ushort_t* f1t   = (ushort_t*)(ws + 4050000);   // 6,553,600 u16
  ushort_t* f0t   = (ushort_t*)(ws + 7330000);   // 26,214,400 u16
  ushort_t* colB  = (ushort_t*)(ws + 20440000);  // 26,214,400 u16 (colC/colT share)
  ushort_t* part  = (ushort_t*)(ws + 33550000);  // 13,107,200 u16 (8 bf16 slices)

  convert_w9<<<(64 * 2304 + 255) / 256, 256, 0, stream>>>(com_w0, Acom0, 48, 64);
  convert_w9<<<(64 * 2304 + 255) / 256, 256, 0, stream>>>(com_w1, Acom1, 48, 64);
  convert_w9<<<(256 * 2304 + 255) / 256, 256, 0, stream>>>(res_w, Ares, 256, 256);
  convert_dcnw<<<512, 256, 0, stream>>>(dcn_w0, dcn_w1, A0, A1);
  nhwc_bf16_kernel<<<dim3(200, 8, 4), 256, 0, stream>>>(f1, f1t, 6400);
  nhwc_bf16_kernel<<<dim3(800, 8, 4), 256, 0, stream>>>(f0, f0t, 25600);

  const float* fsrc = f2;
  for (int s = 0; s < 4; ++s) {
    int l = s & 1;
    // com conv as GEMM (M=48 pad 64, K=2304, split-K 4)
    nhwc_bf16_kernel<<<dim3(50, 8, 4), 256, 0, stream>>>(fsrc, ft40, 1600);
    im2col40<<<dim3(100, 4), 256, 0, stream>>>(ft40, colB);
    gemm_bt<64><<<dim3(50, 1, 4), 256, 0, stream>>>(l ? Acom1 : Acom0, colB, part, 18, 2304);
    // sampler fuses com epilogue (bias + partial-sum + sigmoid)
    if (l == 0) {
      sample_kernel<<<dim3(200, 4), 256, 0, stream>>>(f1t, part, com_b0, colB, 80, 80, 2, 1, 1);
    } else {
      sample_kernel<<<dim3(200, 4), 256, 0, stream>>>(f0t, part, com_b1, colB, 160, 160, 4, 3, 3);
    }
    // deformable conv GEMM (K=4096, split-K 8)
    gemm_bt<128><<<dim3(50, 2, 8), 256, 0, stream>>>(l ? A1 : A0, colB, part, 16, 4096);
    gemm_epilogue<<<dim3(2, 256, 4), 256, 0, stream>>>(part, l ? dcn_b1 : dcn_b0, fsrc, fbuf, 1);
    fsrc = fbuf;
  }
  // res conv as GEMM (M=256, K=2304, split-K 8), epilogue adds f2 (fh)
  nhwc_bf16_kernel<<<dim3(50, 8, 4), 256, 0, stream>>>(fbuf, ft40, 1600);
  im2col40<<<dim3(100, 4), 256, 0, stream>>>(ft40, colB);
  gemm_bt<128><<<dim3(50, 2, 8), 256, 0, stream>>>(Ares, colB, part, 9, 2304);
  gemm_epilogue<<<dim3(2, 256, 4), 256, 0, stream>>>(part, res_b, f2, out, 0);
}

// Round 7
// 568.419 us; speedup vs baseline: 1.2892x; 1.1896x over previous
//
#include <hip/hip_runtime.h>

#define HW40 1600
typedef unsigned short ushort_t;
typedef __attribute__((ext_vector_type(8))) short short8;
typedef __attribute__((ext_vector_type(4))) short short4v;
typedef __attribute__((ext_vector_type(4))) float f4v;

__device__ __forceinline__ float bu(ushort_t u) {
  union { unsigned i; float f; } x; x.i = ((unsigned)u) << 16; return x.f;
}
__device__ __forceinline__ ushort_t fb(float f) {
  union { float f; unsigned i; } x; x.f = f;
  unsigned r = x.i + 0x7FFFu + ((x.i >> 16) & 1u);
  return (ushort_t)(r >> 16);
}

#define GLD16(g, l)                                                            \
  __builtin_amdgcn_global_load_lds(                                            \
      (const __attribute__((address_space(1))) void*)(g),                      \
      (__attribute__((address_space(3))) void*)(l), 16, 0, 0)

#define PART_STRIDE 1638400  // one split-K slice: 256 x 6400

// ---------------------------------------------------------------------------
// zero page for OOB conv taps (ws is poisoned 0xAA before every launch)
// ---------------------------------------------------------------------------
__global__ void zp_init(ushort_t* zp) { zp[threadIdx.x] = 0; }

// ---------------------------------------------------------------------------
// 3x3 conv weights [co][cin][3][3] fp32 -> A[co][tap*256+cin] bf16, pad rows.
// ---------------------------------------------------------------------------
__global__ void convert_w9(const float* __restrict__ src, ushort_t* __restrict__ dst,
                           int Cout_src, int Cout_pad) {
  int idx = blockIdx.x * 256 + threadIdx.x;
  if (idx >= Cout_pad * 2304) return;
  int co = idx / 2304;
  int k  = idx - co * 2304;
  int cin = k & 255, tap = k >> 8;
  dst[idx] = (co < Cout_src) ? fb(src[(size_t)co * 2304 + cin * 9 + tap]) : (ushort_t)0;
}

// ---------------------------------------------------------------------------
// dcn weights [co][cin][16] fp32 -> A_bf16 [co][k = i*256 + cin]
// ---------------------------------------------------------------------------
__global__ __launch_bounds__(256) void convert_dcnw(const float* __restrict__ w0,
                                                    const float* __restrict__ w1,
                                                    ushort_t* __restrict__ A0,
                                                    ushort_t* __restrict__ A1) {
  __shared__ float s[4096];
  const int co = blockIdx.x & 255;
  const float* w = (blockIdx.x < 256) ? w0 : w1;
  ushort_t* A = (blockIdx.x < 256) ? A0 : A1;
  const int t = threadIdx.x;
  const float4* wp = (const float4*)(w + (size_t)co * 4096);
#pragma unroll
  for (int q = 0; q < 4; ++q) ((float4*)s)[t + q * 256] = wp[t + q * 256];
  __syncthreads();
  const int i = t >> 4, cb = (t & 15) * 16;
  ushort_t tmp[16];
#pragma unroll
  for (int j = 0; j < 16; ++j) tmp[j] = fb(s[(cb + j) * 16 + i]);
  ushort_t* op = A + (size_t)co * 4096 + t * 16;
  ((uint4*)op)[0] = ((uint4*)tmp)[0];
  ((uint4*)op)[1] = ((uint4*)tmp)[1];
}

// ---------------------------------------------------------------------------
// NCHW fp32 -> NHWC bf16:  xt[b][s][c] = bf16(x[b][c][s])
// ---------------------------------------------------------------------------
__global__ __launch_bounds__(256) void nhwc_bf16_kernel(const float* __restrict__ x,
                                                        ushort_t* __restrict__ xt, int HW) {
  __shared__ float tile[32][33];
  const int s0 = blockIdx.x * 32, c0 = blockIdx.y * 32, b = blockIdx.z;
  const int tx = threadIdx.x & 31, ty = threadIdx.x >> 5;
  const float* xb = x + ((size_t)b * 256 + c0) * HW + s0;
#pragma unroll
  for (int q = 0; q < 4; ++q) tile[ty + q * 8][tx] = xb[(size_t)(ty + q * 8) * HW + tx];
  __syncthreads();
  ushort_t* ob = xt + ((size_t)b * HW + s0) * 256 + c0;
#pragma unroll
  for (int q = 0; q < 4; ++q) {
    int srow = ty + q * 8;
    ob[(size_t)srow * 256 + tx] = fb(tile[tx][srow]);
  }
}

// ---------------------------------------------------------------------------
// Sampler (fused com-epilogue). XCD-contiguous work swizzle: 1D grid 800,
// work = (g&7)*100 + (g>>3) so each XCD gets one contiguous half-batch of px
// (gather source window ~L2-resident). 8-px tiles, block 256.
// ---------------------------------------------------------------------------
__global__ __launch_bounds__(256) void sample_kernel(
    const ushort_t* __restrict__ xt, const ushort_t* __restrict__ part,
    const float* __restrict__ cbias, ushort_t* __restrict__ colT,
    int Hin, int Win, int stride, int pad, int dil) {
  __shared__ int4  gL[128];
  __shared__ float4 gW[128];
  const int g = blockIdx.x;
  const int work = (g & 7) * 100 + (g >> 3);
  const int b = work / 200;
  const int px0 = (work - b * 200) * 8;
  const int t = threadIdx.x;
  const int HWin = Hin * Win;

  if (t < 128) {  // geometry: pair pid = t -> (px_l = t&7, tap i = t>>3)
    const int px_l = t & 7, i = t >> 3;
    const int p = px0 + px_l;
    const int n = b * 1600 + p;
    const int ph = p / 40, pw = p - (p / 40) * 40;
    float dy = cbias[2 * i], dx = cbias[2 * i + 1], mzr = cbias[32 + i];
#pragma unroll
    for (int kz = 0; kz < 4; ++kz) {
      const ushort_t* pp = part + (size_t)kz * PART_STRIDE + n;
      dy  += bu(pp[(size_t)(2 * i) * 6400]);
      dx  += bu(pp[(size_t)(2 * i + 1) * 6400]);
      mzr += bu(pp[(size_t)(32 + i) * 6400]);
    }
    float mz = 1.f / (1.f + expf(-mzr));
    float py = (float)(ph * stride - pad + (i >> 2) * dil) + dy;
    float px = (float)(pw * stride - pad + (i & 3) * dil) + dx;
    float y0f = floorf(py), x0f = floorf(px);
    float ly = py - y0f, lx = px - x0f;
    int y0 = (int)y0f, x0 = (int)x0f;
    int y1 = y0 + 1, x1 = x0 + 1;
    float hy = 1.f - ly, hx = 1.f - lx;
    float w00 = hy * hx * mz, w01 = hy * lx * mz;
    float w10 = ly * hx * mz, w11 = ly * lx * mz;
    if (y0 < 0 || y0 >= Hin) { w00 = 0.f; w01 = 0.f; }
    if (y1 < 0 || y1 >= Hin) { w10 = 0.f; w11 = 0.f; }
    if (x0 < 0 || x0 >= Win) { w00 = 0.f; w10 = 0.f; }
    if (x1 < 0 || x1 >= Win) { w01 = 0.f; w11 = 0.f; }
    int cy0 = min(max(y0, 0), Hin - 1), cy1 = min(max(y1, 0), Hin - 1);
    int cx0 = min(max(x0, 0), Win - 1), cx1 = min(max(x1, 0), Win - 1);
    gL[t] = make_int4((cy0 * Win + cx0) * 256, (cy0 * Win + cx1) * 256,
                      (cy1 * Win + cx0) * 256, (cy1 * Win + cx1) * 256);
    gW[t] = make_float4(w00, w01, w10, w11);
  }
  __syncthreads();

  const ushort_t* xtb = xt + (size_t)b * HWin * 256;
  const int wv = t >> 6, l = t & 63;
  const int half = l >> 5;
  const int cin8 = (l & 31) * 8;

#pragma unroll 2
  for (int it = 0; it < 16; ++it) {
    const int pr = it * 8 + wv * 2 + half;
    const int4 G = gL[pr];
    const float4 W = gW[pr];
    short8 c00 = *(const short8*)(xtb + G.x + cin8);
    short8 c01 = *(const short8*)(xtb + G.y + cin8);
    short8 c10 = *(const short8*)(xtb + G.z + cin8);
    short8 c11 = *(const short8*)(xtb + G.w + cin8);
    short8 rr;
#pragma unroll
    for (int j = 0; j < 8; ++j) {
      float v = W.x * bu((ushort_t)c00[j]) + W.y * bu((ushort_t)c01[j]) +
                W.z * bu((ushort_t)c10[j]) + W.w * bu((ushort_t)c11[j]);
      rr[j] = (short)fb(v);
    }
    const int px_l = pr & 7, i = pr >> 3;
    *(short8*)(colT + ((size_t)(b * 1600 + px0 + px_l) * 4096 + i * 256 + cin8)) = rr;
  }
}

// ---------------------------------------------------------------------------
// Deform GEMM (K=4096, colT B-matrix), split-K 8, bf16 partials.
// 1D grid 800: kz=g&7, mt=(g>>3)&1, nt=g>>4 -> mt-pairs sharing a B-tile land
// on the same XCD (round-robin g%8). K-chunk swizzle as before.
// ---------------------------------------------------------------------------
__global__ __launch_bounds__(256) void gemm_deform(const ushort_t* __restrict__ A,
                                                   const ushort_t* __restrict__ B,
                                                   ushort_t* __restrict__ part) {
  __shared__ ushort_t sA[128 * 32];
  __shared__ ushort_t sB[128 * 32];
  const int g = blockIdx.x;
  const int kz = g & 7, mt = (g >> 3) & 1, nt = g >> 4;
  const int t = threadIdx.x;
  const int wv = t >> 6, l = t & 63;
  const int wm = wv >> 1, wn = wv & 1;

  f4v acc[4][4];
#pragma unroll
  for (int a = 0; a < 4; ++a)
#pragma unroll
    for (int bb = 0; bb < 4; ++bb) acc[a][bb] = (f4v)(0.f);

  const int ra = t >> 2;
  const int q  = ((t & 3) - (ra >> 1)) & 3;
  const size_t aoff = (size_t)(mt * 128 + ra) * 4096 + q * 8;
  const size_t boff = (size_t)(nt * 128 + ra) * 4096 + q * 8;
  ushort_t* lA = sA + t * 8;
  ushort_t* lB = sB + t * 8;

  int k0 = kz * 512;
  const int lm = l & 15;
  const int koff = (((l >> 4) + (lm >> 1)) & 3) * 8;

  for (int step = 0; step < 16; ++step, k0 += 32) {
    __syncthreads();
    GLD16(A + aoff + k0, lA);
    GLD16(A + aoff + (size_t)64 * 4096 + k0, lA + 2048);
    GLD16(B + boff + k0, lB);
    GLD16(B + boff + (size_t)64 * 4096 + k0, lB + 2048);
    __syncthreads();
    short8 af[4], bfr[4];
#pragma unroll
    for (int fm = 0; fm < 4; ++fm)
      af[fm] = *(const short8*)(sA + (wm * 64 + fm * 16 + lm) * 32 + koff);
#pragma unroll
    for (int fn = 0; fn < 4; ++fn)
      bfr[fn] = *(const short8*)(sB + (wn * 64 + fn * 16 + lm) * 32 + koff);
#pragma unroll
    for (int fm = 0; fm < 4; ++fm)
#pragma unroll
      for (int fn = 0; fn < 4; ++fn)
        acc[fm][fn] = __builtin_amdgcn_mfma_f32_16x16x32_bf16(af[fm], bfr[fn],
                                                              acc[fm][fn], 0, 0, 0);
  }

  const int row_l = (l >> 4) * 4;
  ushort_t* pb = part + (size_t)kz * PART_STRIDE;
#pragma unroll
  for (int fm = 0; fm < 4; ++fm) {
#pragma unroll
    for (int fn = 0; fn < 4; ++fn) {
      const int n = nt * 128 + wn * 64 + fn * 16 + lm;
#pragma unroll
      for (int r = 0; r < 4; ++r) {
        const int m = mt * 128 + wm * 64 + fm * 16 + row_l + r;
        pb[(size_t)m * 6400 + n] = fb(acc[fm][fn][r]);
      }
    }
  }
}

// ---------------------------------------------------------------------------
// 3x3 conv GEMM (com/res) staging B DIRECTLY from NHWC ft40 (no im2col).
// Within a 32-wide K-step the tap is wave-uniform (32 | 256), so lane address
// = ft + n*256 + off(tap) + c0 + q*8; OOB lanes -> zero page. B source is the
// 3.3 MB ft40 (L2/L3-resident). grid 1D = 50 * (MTILE==128?2:1) * KZ.
// ---------------------------------------------------------------------------
template <int MTILE, int KZ>
__global__ __launch_bounds__(256) void gemm_conv3(const ushort_t* __restrict__ A,
                                                  const ushort_t* __restrict__ ft,
                                                  const ushort_t* __restrict__ zp,
                                                  ushort_t* __restrict__ part,
                                                  int ksteps) {
  constexpr int FN = (MTILE == 128) ? 4 : 2;
  __shared__ ushort_t sA[MTILE * 32];
  __shared__ ushort_t sB[128 * 32];
  const int g = blockIdx.x;
  const int kz = g % KZ;
  const int r = g / KZ;
  const int mt = (MTILE == 128) ? (r & 1) : 0;
  const int nt = (MTILE == 128) ? (r >> 1) : r;
  const int t = threadIdx.x;
  const int wv = t >> 6, l = t & 63;
  const int wm = (MTILE == 128) ? (wv >> 1) : 0;
  const int wn = (MTILE == 128) ? (wv & 1) : wv;

  f4v acc[4][FN];
#pragma unroll
  for (int a = 0; a < 4; ++a)
#pragma unroll
    for (int bb = 0; bb < FN; ++bb) acc[a][bb] = (f4v)(0.f);

  const int ra = t >> 2;
  const int q  = ((t & 3) - (ra >> 1)) & 3;
  const int qc = q * 8;
  const size_t aoff = (size_t)(mt * MTILE + ra) * 2304 + qc;
  // B rows: n0 = nt*128+ra (half 0), n1 = n0+64 (half 1)
  const int n0 = nt * 128 + ra;
  const int n1 = n0 + 64;
  const int b0 = n0 / 1600, p0 = n0 - b0 * 1600;
  const int b1 = n1 / 1600, p1 = n1 - b1 * 1600;
  const int ph0 = p0 / 40, pw0 = p0 - (p0 / 40) * 40;
  const int ph1 = p1 / 40, pw1 = p1 - (p1 / 40) * 40;
  const ushort_t* fp0 = ft + (size_t)n0 * 256 + qc;
  const ushort_t* fp1 = ft + (size_t)n1 * 256 + qc;
  ushort_t* lA = sA + t * 8;
  ushort_t* lB = sB + t * 8;

  int k0 = kz * ksteps * 32;
  const int lm = l & 15;
  const int koff = (((l >> 4) + (lm >> 1)) & 3) * 8;

  for (int step = 0; step < ksteps; ++step, k0 += 32) {
    const int tap = k0 >> 8, c0 = k0 & 255;
    const int ky = tap / 3;
    const int dy = ky - 1, dx = (tap - ky * 3) - 1;
    const int off = (dy * 40 + dx) * 256 + c0;
    const bool ok0 = ((unsigned)(ph0 + dy) < 40u) & ((unsigned)(pw0 + dx) < 40u);
    const bool ok1 = ((unsigned)(ph1 + dy) < 40u) & ((unsigned)(pw1 + dx) < 40u);
    const ushort_t* s0 = ok0 ? (fp0 + off) : zp;
    const ushort_t* s1 = ok1 ? (fp1 + off) : zp;
    __syncthreads();
    GLD16(A + aoff + k0, lA);
    if (MTILE == 128) GLD16(A + aoff + (size_t)64 * 2304 + k0, lA + 2048);
    GLD16(s0, lB);
    GLD16(s1, lB + 2048);
    __syncthreads();
    short8 af[4], bfr[FN];
#pragma unroll
    for (int fm = 0; fm < 4; ++fm)
      af[fm] = *(const short8*)(sA + (wm * 64 + fm * 16 + lm) * 32 + koff);
#pragma unroll
    for (int fn = 0; fn < FN; ++fn)
      bfr[fn] = *(const short8*)(sB + (wn * (16 * FN) + fn * 16 + lm) * 32 + koff);
#pragma unroll
    for (int fm = 0; fm < 4; ++fm)
#pragma unroll
      for (int fn = 0; fn < FN; ++fn)
        acc[fm][fn] = __builtin_amdgcn_mfma_f32_16x16x32_bf16(af[fm], bfr[fn],
                                                              acc[fm][fn], 0, 0, 0);
  }

  const int row_l = (l >> 4) * 4;
  ushort_t* pb = part + (size_t)kz * PART_STRIDE;
#pragma unroll
  for (int fm = 0; fm < 4; ++fm) {
#pragma unroll
    for (int fn = 0; fn < FN; ++fn) {
      const int n = nt * 128 + wn * (16 * FN) + fn * 16 + lm;
#pragma unroll
      for (int r = 0; r < 4; ++r) {
        const int m = mt * MTILE + wm * 64 + fm * 16 + row_l + r;
        pb[(size_t)m * 6400 + n] = fb(acc[fm][fn][r]);
      }
    }
  }
}

// ---------------------------------------------------------------------------
// GEMM epilogue: dst = (relu? max(sum8+bias,0) : sum8+bias) + src
// grid (2, 256, B), block 256.
// ---------------------------------------------------------------------------
__global__ __launch_bounds__(256) void gemm_epilogue(const ushort_t* __restrict__ part,
                                                     const float* __restrict__ bias,
                                                     const float* __restrict__ src,
                                                     float* __restrict__ dst, int relu) {
  const int co = blockIdx.y, b = blockIdx.z;
  const int idx = blockIdx.x * 256 + threadIdx.x;
  if (idx >= 400) return;
  const int p = idx * 4;
  const size_t n = (size_t)b * 1600 + p;
  float a[4] = {0.f, 0.f, 0.f, 0.f};
#pragma unroll
  for (int kz = 0; kz < 8; ++kz) {
    short4v pp = *(const short4v*)(part + (size_t)kz * PART_STRIDE + (size_t)co * 6400 + n);
#pragma unroll
    for (int j = 0; j < 4; ++j) a[j] += bu((ushort_t)pp[j]);
  }
  float bv = bias[co];
  const size_t fo = ((size_t)b * 256 + co) * 1600 + p;
  float4 s = *(const float4*)(src + fo);
  float4 o;
  if (relu) {
    o.x = fmaxf(a[0] + bv, 0.f) + s.x;
    o.y = fmaxf(a[1] + bv, 0.f) + s.y;
    o.z = fmaxf(a[2] + bv, 0.f) + s.z;
    o.w = fmaxf(a[3] + bv, 0.f) + s.w;
  } else {
    o.x = a[0] + bv + s.x;
    o.y = a[1] + bv + s.y;
    o.z = a[2] + bv + s.z;
    o.w = a[3] + bv + s.w;
  }
  *(float4*)(dst + fo) = o;
}

// ---------------------------------------------------------------------------
extern "C" void kernel_launch(void* const* d_in, const int* in_sizes, int n_in,
                              void* d_out, int out_size, void* d_ws, size_t ws_size,
                              hipStream_t stream) {
  (void)in_sizes; (void)n_in; (void)out_size; (void)ws_size;
  const float* f0     = (const float*)d_in[0];
  const float* f1     = (const float*)d_in[1];
  const float* f2     = (const float*)d_in[2];
  const float* com_w0 = (const float*)d_in[3];
  const float* com_b0 = (const float*)d_in[4];
  const float* com_w1 = (const float*)d_in[5];
  const float* com_b1 = (const float*)d_in[6];
  const float* dcn_w0 = (const float*)d_in[7];
  const float* dcn_b0 = (const float*)d_in[8];
  const float* dcn_w1 = (const float*)d_in[9];
  const float* dcn_b1 = (const float*)d_in[10];
  const float* res_w  = (const float*)d_in[11];
  const float* res_b  = (const float*)d_in[12];
  float* out = (float*)d_out;
  float* ws  = (float*)d_ws;

  // ws layout (float offsets); ~40.3M floats ~= 161 MB
  float*    fbuf  = ws + 0;          // 1,638,400 f32
  ushort_t* A0    = (ushort_t*)(ws + 1700000);   // 1,048,576 u16
  ushort_t* A1    = (ushort_t*)(ws + 2230000);   // 1,048,576 u16
  ushort_t* Acom0 = (ushort_t*)(ws + 2760000);   //   147,456 u16 (64x2304)
  ushort_t* Acom1 = (ushort_t*)(ws + 2840000);   //   147,456 u16
  ushort_t* Ares  = (ushort_t*)(ws + 2920000);   //   589,824 u16 (256x2304)
  ushort_t* ft40  = (ushort_t*)(ws + 3220000);   // 1,638,400 u16
  ushort_t* f1t   = (ushort_t*)(ws + 4050000);   // 6,553,600 u16
  ushort_t* f0t   = (ushort_t*)(ws + 7330000);   // 26,214,400 u16
  ushort_t* colT  = (ushort_t*)(ws + 20440000);  // 26,214,400 u16
  ushort_t* part  = (ushort_t*)(ws + 33550000);  // 13,107,200 u16 (8 bf16 slices)
  ushort_t* zp    = (ushort_t*)(ws + 40110000);  //       256 u16 zero page

  zp_init<<<1, 256, 0, stream>>>(zp);
  convert_w9<<<(64 * 2304 + 255) / 256, 256, 0, stream>>>(com_w0, Acom0, 48, 64);
  convert_w9<<<(64 * 2304 + 255) / 256, 256, 0, stream>>>(com_w1, Acom1, 48, 64);
  convert_w9<<<(256 * 2304 + 255) / 256, 256, 0, stream>>>(res_w, Ares, 256, 256);
  convert_dcnw<<<512, 256, 0, stream>>>(dcn_w0, dcn_w1, A0, A1);
  nhwc_bf16_kernel<<<dim3(200, 8, 4), 256, 0, stream>>>(f1, f1t, 6400);
  nhwc_bf16_kernel<<<dim3(800, 8, 4), 256, 0, stream>>>(f0, f0t, 25600);

  const float* fsrc = f2;
  for (int s = 0; s < 4; ++s) {
    int l = s & 1;
    // com conv as GEMM (M=48 pad 64, K=2304, split-K 4), B direct from ft40
    nhwc_bf16_kernel<<<dim3(50, 8, 4), 256, 0, stream>>>(fsrc, ft40, 1600);
    gemm_conv3<64, 4><<<200, 256, 0, stream>>>(l ? Acom1 : Acom0, ft40, zp, part, 18);
    // sampler fuses com epilogue (bias + partial-sum + sigmoid)
    if (l == 0) {
      sample_kernel<<<800, 256, 0, stream>>>(f1t, part, com_b0, colT, 80, 80, 2, 1, 1);
    } else {
      sample_kernel<<<800, 256, 0, stream>>>(f0t, part, com_b1, colT, 160, 160, 4, 3, 3);
    }
    // deformable conv GEMM (K=4096, split-K 8)
    gemm_deform<<<800, 256, 0, stream>>>(l ? A1 : A0, colT, part);
    gemm_epilogue<<<dim3(2, 256, 4), 256, 0, stream>>>(part, l ? dcn_b1 : dcn_b0, fsrc, fbuf, 1);
    fsrc = fbuf;
  }
  // res conv as GEMM (M=256, K=2304, split-K 8), B direct from ft40
  nhwc_bf16_kernel<<<dim3(50, 8, 4), 256, 0, stream>>>(fbuf, ft40, 1600);
  gemm_conv3<128, 8><<<800, 256, 0, stream>>>(Ares, ft40, zp, part, 9);
  gemm_epilogue<<<dim3(2, 256, 4), 256, 0, stream>>>(part, res_b, f2, out, 0);
}